// Round 2
// baseline (1030.635 us; speedup 1.0000x reference)
//
#include <hip/hip_runtime.h>
#include <math.h>

#define HIDDEN 4096
#define NEXP 64
#define TOPK 8
#define HC 128            // H chunk per LDS stage
#define LDS_STRIDE 132    // 128 + 4 pad
#define TPW 8             // tokens per wave
#define WAVES 4
#define TPB (TPW * WAVES) // 32 tokens per block

__global__ __launch_bounds__(256, 2)
void moe_gate_kernel(const float* __restrict__ X, const float* __restrict__ W,
                     float* __restrict__ out, int T) {
    __shared__ float wlds[NEXP * LDS_STRIDE];
    const int tid  = threadIdx.x;
    const int lane = tid & 63;           // lane == expert index
    const int wid  = tid >> 6;
    const int t0   = blockIdx.x * TPB + wid * TPW;

    double acc[TPW];
#pragma unroll
    for (int m = 0; m < TPW; ++m) acc[m] = 0.0;

    for (int hb = 0; hb < HIDDEN; hb += HC) {
        __syncthreads();   // previous chunk's reads done before overwrite
        // stage W[0..63][hb..hb+HC-1] -> LDS. 2048 float4, 8 per thread.
#pragma unroll
        for (int k = 0; k < 8; ++k) {
            int f  = tid + k * 256;
            int e  = f >> 5;              // 32 float4 per row
            int c4 = f & 31;
            const float4 wv = *reinterpret_cast<const float4*>(W + e * HIDDEN + hb + c4 * 4);
            *reinterpret_cast<float4*>(&wlds[e * LDS_STRIDE + c4 * 4]) = wv;
        }
        __syncthreads();
#pragma unroll 2
        for (int h4 = 0; h4 < HC / 4; ++h4) {
            const float4 wv = *reinterpret_cast<const float4*>(&wlds[lane * LDS_STRIDE + h4 * 4]);
            const double w0 = (double)wv.x, w1 = (double)wv.y,
                         w2 = (double)wv.z, w3 = (double)wv.w;
#pragma unroll
            for (int m = 0; m < TPW; ++m) {
                const float4 xv = *reinterpret_cast<const float4*>(
                    X + (size_t)(t0 + m) * HIDDEN + hb + h4 * 4);
                acc[m] = fma((double)xv.x, w0, acc[m]);
                acc[m] = fma((double)xv.y, w1, acc[m]);
                acc[m] = fma((double)xv.z, w2, acc[m]);
                acc[m] = fma((double)xv.w, w3, acc[m]);
            }
        }
    }

    // epilogue (f64 compares): softcap -> top-8 (lowest-index tie-break)
    // -> softmax over the 8 (full softmax denominator cancels in renorm)
    float* out_w = out;
    float* out_i = out + (size_t)T * TOPK;
#pragma unroll 1
    for (int m = 0; m < TPW; ++m) {
        const int t = t0 + m;
        double v = 30.0 * tanh(acc[m] * (1.0 / 30.0));
        double vmax0 = 0.0, my_e = 0.0, sum = 0.0;
        int    my_i = 0;
#pragma unroll 1
        for (int k = 0; k < TOPK; ++k) {
            double bv = v;
            int    bi = lane;
#pragma unroll
            for (int s = 32; s >= 1; s >>= 1) {
                double ov = __shfl_xor(bv, s);
                int    oi = __shfl_xor(bi, s);
                if (ov > bv || (ov == bv && oi < bi)) { bv = ov; bi = oi; }
            }
            if (k == 0) vmax0 = bv;
            double e = exp(bv - vmax0);
            sum += e;
            if (lane == k) { my_e = e; my_i = bi; }
            if (lane == bi) v = -HUGE_VAL;   // remove winner for next round
        }
        if (lane < TOPK) {
            out_w[(size_t)t * TOPK + lane] = (float)(my_e / sum);
            out_i[(size_t)t * TOPK + lane] = (float)my_i;  // indices as float
        }
    }
}

extern "C" void kernel_launch(void* const* d_in, const int* in_sizes, int n_in,
                              void* d_out, int out_size, void* d_ws, size_t ws_size,
                              hipStream_t stream) {
    const float* X = (const float*)d_in[0];     // [4,4096,4096] fp32
    const float* W = (const float*)d_in[1];     // [64,4096] fp32
    float* out = (float*)d_out;                 // [T*8] weights ++ [T*8] indices
    const int T = in_sizes[0] / HIDDEN;         // 16384
    const int blocks = T / TPB;                 // 512
    hipLaunchKernelGGL(moe_gate_kernel, dim3(blocks), dim3(256), 0, stream,
                       X, W, out, T);
}

// Round 3
// 510.679 us; speedup vs baseline: 2.0182x; 2.0182x over previous
//
#include <hip/hip_runtime.h>
#include <math.h>

#define HIDDEN 4096
#define NEXP 64
#define TOPK 8
#define HC 64             // H chunk per LDS stage
#define LDS_STRIDE 68     // 64 + 4 pad (16B-aligned rows, spread banks)
#define TPW 4             // tokens per wave
#define WAVES 4
#define TPB (TPW * WAVES) // 16 tokens per block
#define MARGIN 2e-5f      // >> fp32 dot worst-case error (~1e-5)

__global__ __launch_bounds__(256, 4)
void moe_gate_kernel(const float* __restrict__ X, const float* __restrict__ W,
                     float* __restrict__ out, int T) {
    __shared__ float wlds[NEXP * LDS_STRIDE];
    const int tid  = threadIdx.x;
    const int lane = tid & 63;            // lane == expert index
    const int wid  = tid >> 6;
    const int t0   = __builtin_amdgcn_readfirstlane(blockIdx.x * TPB + wid * TPW);

    double accd[TPW];
#pragma unroll
    for (int m = 0; m < TPW; ++m) accd[m] = 0.0;

    for (int hb = 0; hb < HIDDEN; hb += HC) {
        __syncthreads();   // previous chunk's reads done before overwrite
        // stage W[0..63][hb..hb+63] -> LDS: 1024 float4, 4 per thread
#pragma unroll
        for (int k = 0; k < 4; ++k) {
            int f  = tid + k * 256;
            int e  = f >> 4;              // 16 float4 per row
            int c4 = f & 15;
            const float4 wv = *reinterpret_cast<const float4*>(W + e * HIDDEN + hb + c4 * 4);
            *reinterpret_cast<float4*>(&wlds[e * LDS_STRIDE + c4 * 4]) = wv;
        }
        __syncthreads();

        float accf[TPW];
#pragma unroll
        for (int m = 0; m < TPW; ++m) accf[m] = 0.f;

#pragma unroll 4
        for (int h4 = 0; h4 < HC / 4; ++h4) {
            const float4 wv = *reinterpret_cast<const float4*>(&wlds[lane * LDS_STRIDE + h4 * 4]);
#pragma unroll
            for (int m = 0; m < TPW; ++m) {
                const float4 xv = *reinterpret_cast<const float4*>(
                    X + (size_t)(t0 + m) * HIDDEN + hb + h4 * 4);
                accf[m] = fmaf(xv.x, wv.x, accf[m]);
                accf[m] = fmaf(xv.y, wv.y, accf[m]);
                accf[m] = fmaf(xv.z, wv.z, accf[m]);
                accf[m] = fmaf(xv.w, wv.w, accf[m]);
            }
        }
        // fold the 64-element fp32 run into the f64 accumulator
#pragma unroll
        for (int m = 0; m < TPW; ++m) accd[m] += (double)accf[m];
    }

    float* out_w = out;
    float* out_i = out + (size_t)T * TOPK;

#pragma unroll 1
    for (int m = 0; m < TPW; ++m) {
        const int t = t0 + m;
        // ---- fp32 fast path: softcap -> top-9 scan with margin check ----
        float v = 30.0f * tanhf((float)accd[m] * (1.0f / 30.0f));
        float vcur = v;
        float vmax0 = 0.f, my_e = 0.f, sum = 0.f, prev = 0.f;
        int   my_i = 0;
        bool  ambig = false;
#pragma unroll 1
        for (int k = 0; k < TOPK + 1; ++k) {   // 9 rounds: ranks 1..9
            float bv = vcur;
            int   bi = lane;
#pragma unroll
            for (int s = 32; s >= 1; s >>= 1) {
                float ov = __shfl_xor(bv, s);
                int   oi = __shfl_xor(bi, s);
                if (ov > bv || (ov == bv && oi < bi)) { bv = ov; bi = oi; }
            }
            if (k == 0) vmax0 = bv;
            else        ambig |= (prev - bv < MARGIN);   // wave-uniform
            prev = bv;
            if (k < TOPK) {
                float e = __expf(bv - vmax0);
                sum += e;
                if (lane == k) { my_e = e; my_i = bi; }
                if (lane == bi) vcur = -INFINITY;
            }
        }

        if (!ambig) {
            if (lane < TOPK) {
                out_w[(size_t)t * TOPK + lane] = my_e / sum;
                out_i[(size_t)t * TOPK + lane] = (float)my_i;
            }
        } else {
            // ---- exact f64 redo for this token (transposed: lane = h slice) ----
            double lgt = 0.0;
            const float* xr = X + (size_t)t * HIDDEN;
#pragma unroll 1
            for (int e = 0; e < NEXP; ++e) {
                const float* wr = W + (size_t)e * HIDDEN;
                double se = 0.0;
#pragma unroll 2
                for (int hb = 0; hb < HIDDEN; hb += 256) {
                    const float4 wv = *reinterpret_cast<const float4*>(wr + hb + lane * 4);
                    const float4 xv = *reinterpret_cast<const float4*>(xr + hb + lane * 4);
                    se = fma((double)xv.x, (double)wv.x, se);
                    se = fma((double)xv.y, (double)wv.y, se);
                    se = fma((double)xv.z, (double)wv.z, se);
                    se = fma((double)xv.w, (double)wv.w, se);
                }
#pragma unroll
                for (int s = 32; s >= 1; s >>= 1) se += __shfl_xor(se, s);
                if (lane == e) lgt = se;
            }
            double vv = 30.0 * tanh(lgt * (1.0 / 30.0));
            double dmax0 = 0.0, dmy_e = 0.0, dsum = 0.0;
            int    dmy_i = 0;
#pragma unroll 1
            for (int k = 0; k < TOPK; ++k) {
                double bv = vv;
                int    bi = lane;
#pragma unroll
                for (int s = 32; s >= 1; s >>= 1) {
                    double ov = __shfl_xor(bv, s);
                    int    oi = __shfl_xor(bi, s);
                    if (ov > bv || (ov == bv && oi < bi)) { bv = ov; bi = oi; }
                }
                if (k == 0) dmax0 = bv;
                double e = exp(bv - dmax0);
                dsum += e;
                if (lane == k) { dmy_e = e; dmy_i = bi; }
                if (lane == bi) vv = -HUGE_VAL;
            }
            if (lane < TOPK) {
                out_w[(size_t)t * TOPK + lane] = (float)(dmy_e / dsum);
                out_i[(size_t)t * TOPK + lane] = (float)dmy_i;
            }
        }
    }
}

extern "C" void kernel_launch(void* const* d_in, const int* in_sizes, int n_in,
                              void* d_out, int out_size, void* d_ws, size_t ws_size,
                              hipStream_t stream) {
    const float* X = (const float*)d_in[0];     // [4,4096,4096] fp32
    const float* W = (const float*)d_in[1];     // [64,4096] fp32
    float* out = (float*)d_out;                 // [T*8] weights ++ [T*8] indices
    const int T = in_sizes[0] / HIDDEN;         // 16384
    const int blocks = T / TPB;                 // 1024
    hipLaunchKernelGGL(moe_gate_kernel, dim3(blocks), dim3(256), 0, stream,
                       X, W, out, T);
}

// Round 4
// 292.040 us; speedup vs baseline: 3.5291x; 1.7487x over previous
//
#include <hip/hip_runtime.h>
#include <math.h>

#define HIDDEN 4096
#define NEXP 64
#define TOPK 8
#define MARGIN 2.5e-4f

using short8  = __attribute__((ext_vector_type(8))) short;  // 8 bf16 fragment
using floatx4 = __attribute__((ext_vector_type(4))) float;  // MFMA acc

// d_ws layout: [0,4) redo counter | [64, 64+64K) redo token list |
//              [128K, 640K) W_hi bf16[64][4096] | [640K, 1152K) W_lo
#define WS_LIST_OFF (64)
#define WS_WHI_OFF  (128 * 1024)
#define WS_WLO_OFF  (640 * 1024)
#define WS_NEED     (1152 * 1024)

__device__ __forceinline__ unsigned short bf16_rn(float x) {
    unsigned int u = __builtin_bit_cast(unsigned int, x);
    unsigned int r = u + 0x7FFFu + ((u >> 16) & 1u);   // round-to-nearest-even
    return (unsigned short)(r >> 16);
}
__device__ __forceinline__ float bf16_to_f(unsigned short h) {
    unsigned int u = ((unsigned int)h) << 16;
    return __builtin_bit_cast(float, u);
}

// ---------------- pass 0: split W into bf16 hi/lo (runs every call) --------
__global__ void wconv_kernel(const float* __restrict__ W,
                             unsigned short* __restrict__ Whi,
                             unsigned short* __restrict__ Wlo,
                             int* __restrict__ cnt) {
    if (blockIdx.x == 0 && threadIdx.x == 0) *cnt = 0;
    int i = (blockIdx.x * 256 + threadIdx.x) * 4;        // 256 blocks cover 64*4096
    float4 w = *reinterpret_cast<const float4*>(W + i);
    float ws4[4] = {w.x, w.y, w.z, w.w};
    unsigned short h[4], l[4];
#pragma unroll
    for (int j = 0; j < 4; ++j) {
        h[j] = bf16_rn(ws4[j]);
        l[j] = bf16_rn(ws4[j] - bf16_to_f(h[j]));
    }
    using ushort4v = __attribute__((ext_vector_type(4))) unsigned short;
    ushort4v hv = {h[0], h[1], h[2], h[3]};
    ushort4v lv = {l[0], l[1], l[2], l[3]};
    *reinterpret_cast<ushort4v*>(Whi + i) = hv;
    *reinterpret_cast<ushort4v*>(Wlo + i) = lv;
}

// ---------------- pass 1: MFMA gate ----------------------------------------
// block: 256 thr = 4 waves, 16 tokens; wave q does K quarter [q*1024, q*1024+1024)
__global__ __launch_bounds__(256, 3)
void gate_mfma(const float* __restrict__ X,
               const unsigned short* __restrict__ Whi,
               const unsigned short* __restrict__ Wlo,
               float* __restrict__ out,
               int* __restrict__ redo_cnt, int* __restrict__ redo_list, int T) {
    __shared__ float accs[4][16][68];       // [kquarter][token row][expert col+pad]
    const int tid  = threadIdx.x;
    const int lane = tid & 63;
    const int q    = tid >> 6;
    const int t0   = blockIdx.x * 16;
    const int lrow = lane & 15;             // A: token row / B: expert col
    const int kofs = (lane >> 4) * 8;       // per-lane k slice

    floatx4 acc0 = {0.f,0.f,0.f,0.f}, acc1 = {0.f,0.f,0.f,0.f};
    floatx4 acc2 = {0.f,0.f,0.f,0.f}, acc3 = {0.f,0.f,0.f,0.f};

    const float* xrow = X + (size_t)(t0 + lrow) * HIDDEN + q * 1024 + kofs;
    const unsigned short* wh = Whi + (size_t)lrow * HIDDEN + q * 1024 + kofs;
    const unsigned short* wl = Wlo + (size_t)lrow * HIDDEN + q * 1024 + kofs;

#pragma unroll 2
    for (int kb = 0; kb < 1024; kb += 32) {
        // A fragments: 8 fp32 -> bf16 hi/lo
        float4 x0 = *reinterpret_cast<const float4*>(xrow + kb);
        float4 x1 = *reinterpret_cast<const float4*>(xrow + kb + 4);
        float xs[8] = {x0.x, x0.y, x0.z, x0.w, x1.x, x1.y, x1.z, x1.w};
        short8 ah, al;
#pragma unroll
        for (int j = 0; j < 8; ++j) {
            unsigned short h = bf16_rn(xs[j]);
            ah[j] = (short)h;
            al[j] = (short)bf16_rn(xs[j] - bf16_to_f(h));
        }
        // B fragments (4 expert tiles) + 3-term split MFMA
#pragma unroll
        for (int et = 0; et < 4; ++et) {
            const short8 bh = *reinterpret_cast<const short8*>(wh + (size_t)et * 16 * HIDDEN + kb);
            const short8 bl = *reinterpret_cast<const short8*>(wl + (size_t)et * 16 * HIDDEN + kb);
            floatx4& a = (et == 0) ? acc0 : (et == 1) ? acc1 : (et == 2) ? acc2 : acc3;
            a = __builtin_amdgcn_mfma_f32_16x16x32_bf16(ah, bh, a, 0, 0, 0);
            a = __builtin_amdgcn_mfma_f32_16x16x32_bf16(ah, bl, a, 0, 0, 0);
            a = __builtin_amdgcn_mfma_f32_16x16x32_bf16(al, bh, a, 0, 0, 0);
        }
    }

    // D layout: col = lane&15 (+16*et), row = (lane>>4)*4 + r   [m89/m91]
#pragma unroll
    for (int r = 0; r < 4; ++r) {
        const int row = (lane >> 4) * 4 + r;
        accs[q][row][ 0 + lrow] = acc0[r];
        accs[q][row][16 + lrow] = acc1[r];
        accs[q][row][32 + lrow] = acc2[r];
        accs[q][row][48 + lrow] = acc3[r];
    }
    __syncthreads();

    // epilogue: wave q handles rows q*4..q*4+3; lane = expert
    float* out_w = out;
    float* out_i = out + (size_t)T * TOPK;
#pragma unroll 1
    for (int m = 0; m < 4; ++m) {
        const int row = q * 4 + m;
        const int t = t0 + row;
        float lg = accs[0][row][lane] + accs[1][row][lane]
                 + accs[2][row][lane] + accs[3][row][lane];
        float v = 30.0f * tanhf(lg * (1.0f / 30.0f));
        float vcur = v, vmax0 = 0.f, my_e = 0.f, sum = 0.f, prev = 0.f;
        int   my_i = 0;
        bool  ambig = false;
#pragma unroll 1
        for (int k = 0; k < TOPK + 1; ++k) {   // ranks 1..9 with margin check
            float bv = vcur;
            int   bi = lane;
#pragma unroll
            for (int s = 32; s >= 1; s >>= 1) {
                float ov = __shfl_xor(bv, s);
                int   oi = __shfl_xor(bi, s);
                if (ov > bv || (ov == bv && oi < bi)) { bv = ov; bi = oi; }
            }
            if (k == 0) vmax0 = bv;
            else        ambig |= (prev - bv < MARGIN);
            prev = bv;
            if (k < TOPK) {
                float e = __expf(bv - vmax0);
                sum += e;
                if (lane == k) { my_e = e; my_i = bi; }
                if (lane == bi) vcur = -INFINITY;
            }
        }
        if (!ambig) {
            if (lane < TOPK) {
                out_w[(size_t)t * TOPK + lane] = my_e / sum;
                out_i[(size_t)t * TOPK + lane] = (float)my_i;
            }
        } else if (lane == 0) {
            redo_list[atomicAdd(redo_cnt, 1)] = t;
        }
    }
}

// ---------------- pass 2: exact f64 redo of ambiguous tokens ---------------
__global__ __launch_bounds__(256, 2)
void gate_redo(const float* __restrict__ X, const float* __restrict__ W,
               float* __restrict__ out,
               const int* __restrict__ redo_cnt, const int* __restrict__ redo_list,
               int T) {
    __shared__ double lgs[64];
    const int lane = threadIdx.x & 63;
    const int q    = threadIdx.x >> 6;
    const int n    = *redo_cnt;
    float* out_w = out;
    float* out_i = out + (size_t)T * TOPK;

    for (int i = blockIdx.x; i < n; i += gridDim.x) {
        const int t = redo_list[i];
        const float* xr = X + (size_t)t * HIDDEN;
        // wave q computes experts q*16..q*16+15, coalesced lane=h-slice
#pragma unroll 1
        for (int j = 0; j < 16; ++j) {
            const int e = q * 16 + j;
            const float* wr = W + (size_t)e * HIDDEN;
            double s = 0.0;
#pragma unroll 2
            for (int k = lane * 4; k < HIDDEN; k += 256) {
                float4 wv = *reinterpret_cast<const float4*>(wr + k);
                float4 xv = *reinterpret_cast<const float4*>(xr + k);
                s = fma((double)xv.x, (double)wv.x, s);
                s = fma((double)xv.y, (double)wv.y, s);
                s = fma((double)xv.z, (double)wv.z, s);
                s = fma((double)xv.w, (double)wv.w, s);
            }
#pragma unroll
            for (int sft = 32; sft >= 1; sft >>= 1) s += __shfl_xor(s, sft);
            if (lane == 0) lgs[e] = s;
        }
        __syncthreads();
        if (q == 0) {   // exact f64 epilogue on wave 0, lane = expert
            double vv = 30.0 * tanh(lgs[lane] * (1.0 / 30.0));
            double dmax0 = 0.0, dmy_e = 0.0, dsum = 0.0;
            int    dmy_i = 0;
#pragma unroll 1
            for (int k = 0; k < TOPK; ++k) {
                double bv = vv;
                int    bi = lane;
#pragma unroll
                for (int s = 32; s >= 1; s >>= 1) {
                    double ov = __shfl_xor(bv, s);
                    int    oi = __shfl_xor(bi, s);
                    if (ov > bv || (ov == bv && oi < bi)) { bv = ov; bi = oi; }
                }
                if (k == 0) dmax0 = bv;
                double e = exp(bv - dmax0);
                dsum += e;
                if (lane == k) { dmy_e = e; dmy_i = bi; }
                if (lane == bi) vv = -HUGE_VAL;
            }
            if (lane < TOPK) {
                out_w[(size_t)t * TOPK + lane] = (float)(dmy_e / dsum);
                out_i[(size_t)t * TOPK + lane] = (float)dmy_i;
            }
        }
        __syncthreads();
    }
}

// ---------------- fallback (round-3 proven) if ws too small ----------------
#define F_HC 64
#define F_LDS_STRIDE 68
#define F_TPW 4
#define F_TPB 16

__global__ __launch_bounds__(256, 4)
void moe_gate_fallback(const float* __restrict__ X, const float* __restrict__ W,
                       float* __restrict__ out, int T) {
    __shared__ float wlds[NEXP * F_LDS_STRIDE];
    const int tid  = threadIdx.x;
    const int lane = tid & 63;
    const int wid  = tid >> 6;
    const int t0   = blockIdx.x * F_TPB + wid * F_TPW;
    double accd[F_TPW];
#pragma unroll
    for (int m = 0; m < F_TPW; ++m) accd[m] = 0.0;
    for (int hb = 0; hb < HIDDEN; hb += F_HC) {
        __syncthreads();
#pragma unroll
        for (int k = 0; k < 4; ++k) {
            int f = tid + k * 256, e = f >> 4, c4 = f & 15;
            const float4 wv = *reinterpret_cast<const float4*>(W + e * HIDDEN + hb + c4 * 4);
            *reinterpret_cast<float4*>(&wlds[e * F_LDS_STRIDE + c4 * 4]) = wv;
        }
        __syncthreads();
        float accf[F_TPW];
#pragma unroll
        for (int m = 0; m < F_TPW; ++m) accf[m] = 0.f;
#pragma unroll 4
        for (int h4 = 0; h4 < F_HC / 4; ++h4) {
            const float4 wv = *reinterpret_cast<const float4*>(&wlds[lane * F_LDS_STRIDE + h4 * 4]);
#pragma unroll
            for (int m = 0; m < F_TPW; ++m) {
                const float4 xv = *reinterpret_cast<const float4*>(
                    X + (size_t)(t0 + m) * HIDDEN + hb + h4 * 4);
                accf[m] = fmaf(xv.x, wv.x, accf[m]);
                accf[m] = fmaf(xv.y, wv.y, accf[m]);
                accf[m] = fmaf(xv.z, wv.z, accf[m]);
                accf[m] = fmaf(xv.w, wv.w, accf[m]);
            }
        }
#pragma unroll
        for (int m = 0; m < F_TPW; ++m) accd[m] += (double)accf[m];
    }
    float* out_w = out;
    float* out_i = out + (size_t)T * TOPK;
#pragma unroll 1
    for (int m = 0; m < F_TPW; ++m) {
        const int t = t0 + m;
        double vv = 30.0 * tanh(accd[m] * (1.0 / 30.0));
        double dmax0 = 0.0, dmy_e = 0.0, dsum = 0.0;
        int dmy_i = 0;
#pragma unroll 1
        for (int k = 0; k < TOPK; ++k) {
            double bv = vv; int bi = lane;
#pragma unroll
            for (int s = 32; s >= 1; s >>= 1) {
                double ov = __shfl_xor(bv, s);
                int    oi = __shfl_xor(bi, s);
                if (ov > bv || (ov == bv && oi < bi)) { bv = ov; bi = oi; }
            }
            if (k == 0) dmax0 = bv;
            double e = exp(bv - dmax0);
            dsum += e;
            if (lane == k) { dmy_e = e; dmy_i = bi; }
            if (lane == bi) vv = -HUGE_VAL;
        }
        if (lane < TOPK) {
            out_w[(size_t)t * TOPK + lane] = (float)(dmy_e / dsum);
            out_i[(size_t)t * TOPK + lane] = (float)dmy_i;
        }
    }
}

extern "C" void kernel_launch(void* const* d_in, const int* in_sizes, int n_in,
                              void* d_out, int out_size, void* d_ws, size_t ws_size,
                              hipStream_t stream) {
    const float* X = (const float*)d_in[0];     // [4,4096,4096] fp32
    const float* W = (const float*)d_in[1];     // [64,4096] fp32
    float* out = (float*)d_out;
    const int T = in_sizes[0] / HIDDEN;         // 16384

    if (ws_size < WS_NEED) {
        hipLaunchKernelGGL(moe_gate_fallback, dim3(T / F_TPB), dim3(256), 0, stream, X, W, out, T);
        return;
    }
    char* ws = (char*)d_ws;
    int* cnt  = (int*)ws;
    int* list = (int*)(ws + WS_LIST_OFF);
    unsigned short* Whi = (unsigned short*)(ws + WS_WHI_OFF);
    unsigned short* Wlo = (unsigned short*)(ws + WS_WLO_OFF);

    hipLaunchKernelGGL(wconv_kernel, dim3(256), dim3(256), 0, stream, W, Whi, Wlo, cnt);
    hipLaunchKernelGGL(gate_mfma, dim3(T / 16), dim3(256), 0, stream,
                       X, Whi, Wlo, out, cnt, list, T);
    hipLaunchKernelGGL(gate_redo, dim3(128), dim3(256), 0, stream,
                       X, W, out, cnt, list, T);
}

// Round 5
// 247.689 us; speedup vs baseline: 4.1610x; 1.1791x over previous
//
#include <hip/hip_runtime.h>
#include <math.h>

#define HIDDEN 4096
#define NEXP 64
#define TOPK 8
#define MARGIN 2.5e-4f

using short8   = __attribute__((ext_vector_type(8))) short;   // 8 bf16 fragment
using floatx4  = __attribute__((ext_vector_type(4))) float;   // MFMA acc
using ushort4v = __attribute__((ext_vector_type(4))) unsigned short;

// d_ws layout: [0,4) redo counter | [64, 64+64K) redo token list |
//              [128K, 640K) W_hi bf16[64][4096] | [640K, 1152K) W_lo
#define WS_LIST_OFF (64)
#define WS_WHI_OFF  (128 * 1024)
#define WS_WLO_OFF  (640 * 1024)
#define WS_NEED     (1152 * 1024)

__device__ __forceinline__ unsigned short bf16_rn(float x) {
    unsigned int u = __builtin_bit_cast(unsigned int, x);
    unsigned int r = u + 0x7FFFu + ((u >> 16) & 1u);   // round-to-nearest-even
    return (unsigned short)(r >> 16);
}
__device__ __forceinline__ float bf16_to_f(unsigned short h) {
    unsigned int u = ((unsigned int)h) << 16;
    return __builtin_bit_cast(float, u);
}

// ---------------- pass 0: split W into bf16 hi/lo (RN, runs every call) ----
__global__ void wconv_kernel(const float* __restrict__ W,
                             unsigned short* __restrict__ Whi,
                             unsigned short* __restrict__ Wlo,
                             int* __restrict__ cnt) {
    if (blockIdx.x == 0 && threadIdx.x == 0) *cnt = 0;
    int i = (blockIdx.x * 256 + threadIdx.x) * 4;
    float4 w = *reinterpret_cast<const float4*>(W + i);
    float ws4[4] = {w.x, w.y, w.z, w.w};
    unsigned short h[4], l[4];
#pragma unroll
    for (int j = 0; j < 4; ++j) {
        h[j] = bf16_rn(ws4[j]);
        l[j] = bf16_rn(ws4[j] - bf16_to_f(h[j]));
    }
    ushort4v hv = {h[0], h[1], h[2], h[3]};
    ushort4v lv = {l[0], l[1], l[2], l[3]};
    *reinterpret_cast<ushort4v*>(Whi + i) = hv;
    *reinterpret_cast<ushort4v*>(Wlo + i) = lv;
}

// ---------------- pass 1: MFMA gate ----------------------------------------
// 512 thr = 8 waves; block owns 16 tokens; wave q does K slice [q*512, q*512+512)
__global__ __launch_bounds__(512, 4)
void gate_mfma(const float* __restrict__ X,
               const unsigned short* __restrict__ Whi,
               const unsigned short* __restrict__ Wlo,
               float* __restrict__ out,
               int* __restrict__ redo_cnt, int* __restrict__ redo_list, int T) {
    __shared__ float accs[8][16][68];       // [kslice][token row][expert col+pad]
    const int tid  = threadIdx.x;
    const int lane = tid & 63;
    const int q    = tid >> 6;              // 0..7
    const int t0   = blockIdx.x * 16;
    const int lrow = lane & 15;             // A: token row / B: expert col
    const int kofs = (lane >> 4) * 8;       // per-lane k slice

    floatx4 acc0 = {0.f,0.f,0.f,0.f}, acc1 = {0.f,0.f,0.f,0.f};
    floatx4 acc2 = {0.f,0.f,0.f,0.f}, acc3 = {0.f,0.f,0.f,0.f};

    const float* xrow = X + (size_t)(t0 + lrow) * HIDDEN + q * 512 + kofs;
    const unsigned short* wh = Whi + (size_t)lrow * HIDDEN + q * 512 + kofs;
    const unsigned short* wl = Wlo + (size_t)lrow * HIDDEN + q * 512 + kofs;

    // preload first X pair (double-buffered across iterations)
    float4 cx0 = *reinterpret_cast<const float4*>(xrow);
    float4 cx1 = *reinterpret_cast<const float4*>(xrow + 4);

#pragma unroll 4
    for (int kb = 0; kb < 512; kb += 32) {
        // --- issue next-iteration X loads (clamped addr keeps it in-bounds) ---
        const int nb = (kb + 32 < 512) ? kb + 32 : 0;
        const float4 nx0 = *reinterpret_cast<const float4*>(xrow + nb);
        const float4 nx1 = *reinterpret_cast<const float4*>(xrow + nb + 4);
        // --- issue ALL 8 B loads up front (independent, stay in flight) ---
        const short8 bh0 = *reinterpret_cast<const short8*>(wh + 0 * 16 * HIDDEN + kb);
        const short8 bh1 = *reinterpret_cast<const short8*>(wh + 1 * 16 * HIDDEN + kb);
        const short8 bh2 = *reinterpret_cast<const short8*>(wh + 2 * 16 * HIDDEN + kb);
        const short8 bh3 = *reinterpret_cast<const short8*>(wh + 3 * 16 * HIDDEN + kb);
        const short8 bl0 = *reinterpret_cast<const short8*>(wl + 0 * 16 * HIDDEN + kb);
        const short8 bl1 = *reinterpret_cast<const short8*>(wl + 1 * 16 * HIDDEN + kb);
        const short8 bl2 = *reinterpret_cast<const short8*>(wl + 2 * 16 * HIDDEN + kb);
        const short8 bl3 = *reinterpret_cast<const short8*>(wl + 3 * 16 * HIDDEN + kb);

        // --- convert current X to bf16 hi/lo (truncation split: 4 ops/elem) ---
        float xs[8] = {cx0.x, cx0.y, cx0.z, cx0.w, cx1.x, cx1.y, cx1.z, cx1.w};
        short8 ah, al;
#pragma unroll
        for (int j = 0; j < 8; ++j) {
            unsigned int u = __builtin_bit_cast(unsigned int, xs[j]);
            ah[j] = (short)(u >> 16);
            float xh = __builtin_bit_cast(float, u & 0xFFFF0000u);
            al[j] = (short)(__builtin_bit_cast(unsigned int, xs[j] - xh) >> 16);
        }

        // --- 12 MFMAs, term-major: consecutive MFMAs hit different accs ---
        acc0 = __builtin_amdgcn_mfma_f32_16x16x32_bf16(ah, bh0, acc0, 0, 0, 0);
        acc1 = __builtin_amdgcn_mfma_f32_16x16x32_bf16(ah, bh1, acc1, 0, 0, 0);
        acc2 = __builtin_amdgcn_mfma_f32_16x16x32_bf16(ah, bh2, acc2, 0, 0, 0);
        acc3 = __builtin_amdgcn_mfma_f32_16x16x32_bf16(ah, bh3, acc3, 0, 0, 0);
        acc0 = __builtin_amdgcn_mfma_f32_16x16x32_bf16(ah, bl0, acc0, 0, 0, 0);
        acc1 = __builtin_amdgcn_mfma_f32_16x16x32_bf16(ah, bl1, acc1, 0, 0, 0);
        acc2 = __builtin_amdgcn_mfma_f32_16x16x32_bf16(ah, bl2, acc2, 0, 0, 0);
        acc3 = __builtin_amdgcn_mfma_f32_16x16x32_bf16(ah, bl3, acc3, 0, 0, 0);
        acc0 = __builtin_amdgcn_mfma_f32_16x16x32_bf16(al, bh0, acc0, 0, 0, 0);
        acc1 = __builtin_amdgcn_mfma_f32_16x16x32_bf16(al, bh1, acc1, 0, 0, 0);
        acc2 = __builtin_amdgcn_mfma_f32_16x16x32_bf16(al, bh2, acc2, 0, 0, 0);
        acc3 = __builtin_amdgcn_mfma_f32_16x16x32_bf16(al, bh3, acc3, 0, 0, 0);

        cx0 = nx0; cx1 = nx1;
    }

    // D layout: col = lane&15 (+16*et), row = (lane>>4)*4 + r   [verified r4]
#pragma unroll
    for (int r = 0; r < 4; ++r) {
        const int row = (lane >> 4) * 4 + r;
        accs[q][row][ 0 + lrow] = acc0[r];
        accs[q][row][16 + lrow] = acc1[r];
        accs[q][row][32 + lrow] = acc2[r];
        accs[q][row][48 + lrow] = acc3[r];
    }
    __syncthreads();

    // epilogue: wave q handles rows 2q, 2q+1; lane = expert
    float* out_w = out;
    float* out_i = out + (size_t)T * TOPK;
#pragma unroll 1
    for (int m = 0; m < 2; ++m) {
        const int row = q * 2 + m;
        const int t = t0 + row;
        float lg = 0.f;
#pragma unroll
        for (int p = 0; p < 8; ++p) lg += accs[p][row][lane];
        float v = 30.0f * tanhf(lg * (1.0f / 30.0f));
        float vcur = v, vmax0 = 0.f, my_e = 0.f, sum = 0.f, prev = 0.f;
        int   my_i = 0;
        bool  ambig = false;
#pragma unroll 1
        for (int k = 0; k < TOPK + 1; ++k) {   // ranks 1..9 with margin check
            float bv = vcur;
            int   bi = lane;
#pragma unroll
            for (int s = 32; s >= 1; s >>= 1) {
                float ov = __shfl_xor(bv, s);
                int   oi = __shfl_xor(bi, s);
                if (ov > bv || (ov == bv && oi < bi)) { bv = ov; bi = oi; }
            }
            if (k == 0) vmax0 = bv;
            else        ambig |= (prev - bv < MARGIN);
            prev = bv;
            if (k < TOPK) {
                float e = __expf(bv - vmax0);
                sum += e;
                if (lane == k) { my_e = e; my_i = bi; }
                if (lane == bi) vcur = -INFINITY;
            }
        }
        if (!ambig) {
            if (lane < TOPK) {
                out_w[(size_t)t * TOPK + lane] = my_e / sum;
                out_i[(size_t)t * TOPK + lane] = (float)my_i;
            }
        } else if (lane == 0) {
            redo_list[atomicAdd(redo_cnt, 1)] = t;
        }
    }
}

// ---------------- pass 2: exact f64 redo of ambiguous tokens ---------------
__global__ __launch_bounds__(256, 2)
void gate_redo(const float* __restrict__ X, const float* __restrict__ W,
               float* __restrict__ out,
               const int* __restrict__ redo_cnt, const int* __restrict__ redo_list,
               int T) {
    __shared__ double lgs[64];
    const int lane = threadIdx.x & 63;
    const int q    = threadIdx.x >> 6;
    const int n    = *redo_cnt;
    float* out_w = out;
    float* out_i = out + (size_t)T * TOPK;

    for (int i = blockIdx.x; i < n; i += gridDim.x) {
        const int t = redo_list[i];
        const float* xr = X + (size_t)t * HIDDEN;
#pragma unroll 1
        for (int j = 0; j < 16; ++j) {
            const int e = q * 16 + j;
            const float* wr = W + (size_t)e * HIDDEN;
            double s = 0.0;
#pragma unroll 2
            for (int k = lane * 4; k < HIDDEN; k += 256) {
                float4 wv = *reinterpret_cast<const float4*>(wr + k);
                float4 xv = *reinterpret_cast<const float4*>(xr + k);
                s = fma((double)xv.x, (double)wv.x, s);
                s = fma((double)xv.y, (double)wv.y, s);
                s = fma((double)xv.z, (double)wv.z, s);
                s = fma((double)xv.w, (double)wv.w, s);
            }
#pragma unroll
            for (int sft = 32; sft >= 1; sft >>= 1) s += __shfl_xor(s, sft);
            if (lane == 0) lgs[e] = s;
        }
        __syncthreads();
        if (q == 0) {
            double vv = 30.0 * tanh(lgs[lane] * (1.0 / 30.0));
            double dmax0 = 0.0, dmy_e = 0.0, dsum = 0.0;
            int    dmy_i = 0;
#pragma unroll 1
            for (int k = 0; k < TOPK; ++k) {
                double bv = vv;
                int    bi = lane;
#pragma unroll
                for (int s = 32; s >= 1; s >>= 1) {
                    double ov = __shfl_xor(bv, s);
                    int    oi = __shfl_xor(bi, s);
                    if (ov > bv || (ov == bv && oi < bi)) { bv = ov; bi = oi; }
                }
                if (k == 0) dmax0 = bv;
                double e = exp(bv - dmax0);
                dsum += e;
                if (lane == k) { dmy_e = e; dmy_i = bi; }
                if (lane == bi) vv = -HUGE_VAL;
            }
            if (lane < TOPK) {
                out_w[(size_t)t * TOPK + lane] = (float)(dmy_e / dsum);
                out_i[(size_t)t * TOPK + lane] = (float)dmy_i;
            }
        }
        __syncthreads();
    }
}

// ---------------- fallback (round-3 proven) if ws too small ----------------
#define F_HC 64
#define F_LDS_STRIDE 68
#define F_TPW 4
#define F_TPB 16

__global__ __launch_bounds__(256, 4)
void moe_gate_fallback(const float* __restrict__ X, const float* __restrict__ W,
                       float* __restrict__ out, int T) {
    __shared__ float wlds[NEXP * F_LDS_STRIDE];
    const int tid  = threadIdx.x;
    const int lane = tid & 63;
    const int wid  = tid >> 6;
    const int t0   = blockIdx.x * F_TPB + wid * F_TPW;
    double accd[F_TPW];
#pragma unroll
    for (int m = 0; m < F_TPW; ++m) accd[m] = 0.0;
    for (int hb = 0; hb < HIDDEN; hb += F_HC) {
        __syncthreads();
#pragma unroll
        for (int k = 0; k < 4; ++k) {
            int f = tid + k * 256, e = f >> 4, c4 = f & 15;
            const float4 wv = *reinterpret_cast<const float4*>(W + e * HIDDEN + hb + c4 * 4);
            *reinterpret_cast<float4*>(&wlds[e * F_LDS_STRIDE + c4 * 4]) = wv;
        }
        __syncthreads();
        float accf[F_TPW];
#pragma unroll
        for (int m = 0; m < F_TPW; ++m) accf[m] = 0.f;
#pragma unroll 4
        for (int h4 = 0; h4 < F_HC / 4; ++h4) {
            const float4 wv = *reinterpret_cast<const float4*>(&wlds[lane * F_LDS_STRIDE + h4 * 4]);
#pragma unroll
            for (int m = 0; m < F_TPW; ++m) {
                const float4 xv = *reinterpret_cast<const float4*>(
                    X + (size_t)(t0 + m) * HIDDEN + hb + h4 * 4);
                accf[m] = fmaf(xv.x, wv.x, accf[m]);
                accf[m] = fmaf(xv.y, wv.y, accf[m]);
                accf[m] = fmaf(xv.z, wv.z, accf[m]);
                accf[m] = fmaf(xv.w, wv.w, accf[m]);
            }
        }
#pragma unroll
        for (int m = 0; m < F_TPW; ++m) accd[m] += (double)accf[m];
    }
    float* out_w = out;
    float* out_i = out + (size_t)T * TOPK;
#pragma unroll 1
    for (int m = 0; m < F_TPW; ++m) {
        const int t = t0 + m;
        double vv = 30.0 * tanh(accd[m] * (1.0 / 30.0));
        double dmax0 = 0.0, dmy_e = 0.0, dsum = 0.0;
        int dmy_i = 0;
#pragma unroll 1
        for (int k = 0; k < TOPK; ++k) {
            double bv = vv; int bi = lane;
#pragma unroll
            for (int s = 32; s >= 1; s >>= 1) {
                double ov = __shfl_xor(bv, s);
                int    oi = __shfl_xor(bi, s);
                if (ov > bv || (ov == bv && oi < bi)) { bv = ov; bi = oi; }
            }
            if (k == 0) dmax0 = bv;
            double e = exp(bv - dmax0);
            dsum += e;
            if (lane == k) { dmy_e = e; dmy_i = bi; }
            if (lane == bi) vv = -HUGE_VAL;
        }
        if (lane < TOPK) {
            out_w[(size_t)t * TOPK + lane] = (float)(dmy_e / dsum);
            out_i[(size_t)t * TOPK + lane] = (float)dmy_i;
        }
    }
}

extern "C" void kernel_launch(void* const* d_in, const int* in_sizes, int n_in,
                              void* d_out, int out_size, void* d_ws, size_t ws_size,
                              hipStream_t stream) {
    const float* X = (const float*)d_in[0];     // [4,4096,4096] fp32
    const float* W = (const float*)d_in[1];     // [64,4096] fp32
    float* out = (float*)d_out;
    const int T = in_sizes[0] / HIDDEN;         // 16384

    if (ws_size < WS_NEED) {
        hipLaunchKernelGGL(moe_gate_fallback, dim3(T / F_TPB), dim3(256), 0, stream, X, W, out, T);
        return;
    }
    char* ws = (char*)d_ws;
    int* cnt  = (int*)ws;
    int* list = (int*)(ws + WS_LIST_OFF);
    unsigned short* Whi = (unsigned short*)(ws + WS_WHI_OFF);
    unsigned short* Wlo = (unsigned short*)(ws + WS_WLO_OFF);

    hipLaunchKernelGGL(wconv_kernel, dim3(256), dim3(256), 0, stream, W, Whi, Wlo, cnt);
    hipLaunchKernelGGL(gate_mfma, dim3(T / 16), dim3(512), 0, stream,
                       X, Whi, Wlo, out, cnt, list, T);
    hipLaunchKernelGGL(gate_redo, dim3(256), dim3(256), 0, stream,
                       X, W, out, cnt, list, T);
}

// Round 6
// 194.330 us; speedup vs baseline: 5.3035x; 1.2746x over previous
//
#include <hip/hip_runtime.h>
#include <math.h>

#define HIDDEN 4096
#define NEXP 64
#define TOPK 8
#define MARGIN 2.5e-4f
#define BK 64
#define TPB 32            // tokens per block
#define NCHUNK (HIDDEN / BK)

using short8   = __attribute__((ext_vector_type(8))) short;   // 8 bf16 fragment
using floatx4  = __attribute__((ext_vector_type(4))) float;   // MFMA acc
using ushort4v = __attribute__((ext_vector_type(4))) unsigned short;

// d_ws layout: [0,4) redo counter | [64, 64+64K) redo token list |
//              [128K, 640K) W_hi bf16[64][4096] | [640K, 1152K) W_lo
#define WS_LIST_OFF (64)
#define WS_WHI_OFF  (128 * 1024)
#define WS_WLO_OFF  (640 * 1024)
#define WS_NEED     (1152 * 1024)

__device__ __forceinline__ unsigned short bf16_rn(float x) {
    unsigned int u = __builtin_bit_cast(unsigned int, x);
    unsigned int r = u + 0x7FFFu + ((u >> 16) & 1u);   // round-to-nearest-even
    return (unsigned short)(r >> 16);
}
__device__ __forceinline__ float bf16_to_f(unsigned short h) {
    unsigned int u = ((unsigned int)h) << 16;
    return __builtin_bit_cast(float, u);
}

__device__ __forceinline__ void gload16(const void* g, void* l) {
    __builtin_amdgcn_global_load_lds(
        (const __attribute__((address_space(1))) void*)g,
        (__attribute__((address_space(3))) void*)l, 16, 0, 0);
}

// ---------------- pass 0: split W into bf16 hi/lo (RN, runs every call) ----
__global__ void wconv_kernel(const float* __restrict__ W,
                             unsigned short* __restrict__ Whi,
                             unsigned short* __restrict__ Wlo,
                             int* __restrict__ cnt) {
    if (blockIdx.x == 0 && threadIdx.x == 0) *cnt = 0;
    int i = (blockIdx.x * 256 + threadIdx.x) * 4;
    float4 w = *reinterpret_cast<const float4*>(W + i);
    float ws4[4] = {w.x, w.y, w.z, w.w};
    unsigned short h[4], l[4];
#pragma unroll
    for (int j = 0; j < 4; ++j) {
        h[j] = bf16_rn(ws4[j]);
        l[j] = bf16_rn(ws4[j] - bf16_to_f(h[j]));
    }
    ushort4v hv = {h[0], h[1], h[2], h[3]};
    ushort4v lv = {l[0], l[1], l[2], l[3]};
    *reinterpret_cast<ushort4v*>(Whi + i) = hv;
    *reinterpret_cast<ushort4v*>(Wlo + i) = lv;
}

// ---------------- pass 1: MFMA gate, LDS-staged via global_load_lds --------
// 512 thr = 8 waves; block owns 32 tokens x 64 experts.
// Wave q: token-tile tt=q>>2 (16 tokens), expert-tile et=q&3 (16 experts).
// LDS: X [32][64] f32 8KB | Whi [64][64] bf16 8KB | Wlo 8KB, all dbuf = 48KB.
// Swizzle (both sides, rule #21): byte ^= (row&7)<<4.
#define XBUF(b)  (smem + (b) * 8192)
#define WHBUF(b) (smem + 16384 + (b) * 8192)
#define WLBUF(b) (smem + 32768 + (b) * 8192)

__global__ __launch_bounds__(512, 4)
void gate_mfma(const float* __restrict__ X,
               const unsigned short* __restrict__ Whi,
               const unsigned short* __restrict__ Wlo,
               float* __restrict__ out,
               int* __restrict__ redo_cnt, int* __restrict__ redo_list, int T) {
    __shared__ __align__(16) char smem[49152];
    const int tid  = threadIdx.x;
    const int lane = tid & 63;
    const int q    = tid >> 6;              // 0..7
    const int tt   = q >> 2;                // 0..1
    const int et   = q & 3;                 // 0..3
    const int t0   = blockIdx.x * TPB;

    // --- staging: wave q issues slots 3q..3q+2 (24 gload_lds per chunk) ---
    auto stage = [&](int buf, int kb) {     // kb in elements
#pragma unroll
        for (int j = 0; j < 3; ++j) {
            const int s = q * 3 + j;
            if (s < 8) {                    // X rows 4s..4s+3
                const int r  = s * 4 + (lane >> 4);
                const int cb = (lane & 15) * 16;
                const int sw = cb ^ ((r & 7) << 4);
                gload16(X + (size_t)(t0 + r) * HIDDEN + kb + (sw >> 2),
                        XBUF(buf) + s * 1024);
            } else if (s < 16) {            // Whi rows 8i..8i+7
                const int i  = s - 8;
                const int r  = i * 8 + (lane >> 3);
                const int cb = (lane & 7) * 16;
                const int sw = cb ^ ((r & 7) << 4);
                gload16(Whi + (size_t)r * HIDDEN + kb + (sw >> 1),
                        WHBUF(buf) + i * 1024);
            } else {                        // Wlo rows
                const int i  = s - 16;
                const int r  = i * 8 + (lane >> 3);
                const int cb = (lane & 7) * 16;
                const int sw = cb ^ ((r & 7) << 4);
                gload16(Wlo + (size_t)r * HIDDEN + kb + (sw >> 1),
                        WLBUF(buf) + i * 1024);
            }
        }
    };

    floatx4 acc = {0.f, 0.f, 0.f, 0.f};
    const int arow = tt * 16 + (lane & 15);       // LDS X row
    const int brow = et * 16 + (lane & 15);       // LDS W row
    const int asz  = (arow & 7) << 4;
    const int bsz  = (brow & 7) << 4;

    stage(0, 0);
    __syncthreads();

#pragma unroll 1
    for (int c = 0; c < NCHUNK; ++c) {
        if (c + 1 < NCHUNK) stage((c + 1) & 1, (c + 1) * BK);
        const char* xb = XBUF(c & 1);
        const char* hb = WHBUF(c & 1);
        const char* lb = WLBUF(c & 1);
#pragma unroll
        for (int ks = 0; ks < 2; ++ks) {
            const int ab0 = ks * 128 + (lane >> 4) * 32;
            const float4 xa = *reinterpret_cast<const float4*>(xb + arow * 256 + ((ab0     ) ^ asz));
            const float4 xc = *reinterpret_cast<const float4*>(xb + arow * 256 + ((ab0 + 16) ^ asz));
            const int bb0 = ks * 64 + (lane >> 4) * 16;
            const short8 bh = *reinterpret_cast<const short8*>(hb + brow * 128 + (bb0 ^ bsz));
            const short8 bl = *reinterpret_cast<const short8*>(lb + brow * 128 + (bb0 ^ bsz));
            float xs[8] = {xa.x, xa.y, xa.z, xa.w, xc.x, xc.y, xc.z, xc.w};
            short8 ah, al;
#pragma unroll
            for (int jj = 0; jj < 8; ++jj) {
                unsigned int u = __builtin_bit_cast(unsigned int, xs[jj]);
                ah[jj] = (short)(u >> 16);
                float xh = __builtin_bit_cast(float, u & 0xFFFF0000u);
                al[jj] = (short)(__builtin_bit_cast(unsigned int, xs[jj] - xh) >> 16);
            }
            acc = __builtin_amdgcn_mfma_f32_16x16x32_bf16(ah, bh, acc, 0, 0, 0);
            acc = __builtin_amdgcn_mfma_f32_16x16x32_bf16(ah, bl, acc, 0, 0, 0);
            acc = __builtin_amdgcn_mfma_f32_16x16x32_bf16(al, bh, acc, 0, 0, 0);
        }
        __syncthreads();   // drains staging vmcnt + protects buffer swap
    }

    // D layout (verified r4/r5): col = lane&15 (expert), row = (lane>>4)*4 + r (token)
    float* accs = reinterpret_cast<float*>(smem);   // [32][68] overlay
    const int drow = tt * 16 + (lane >> 4) * 4;
    const int dcol = et * 16 + (lane & 15);
#pragma unroll
    for (int r = 0; r < 4; ++r) accs[(drow + r) * 68 + dcol] = acc[r];
    __syncthreads();

    // epilogue: wave q handles token rows 4q..4q+3; lane = expert
    float* out_w = out;
    float* out_i = out + (size_t)T * TOPK;
#pragma unroll 1
    for (int m = 0; m < 4; ++m) {
        const int row = q * 4 + m;
        const int t = t0 + row;
        float lg = accs[row * 68 + lane];
        float v = 30.0f * tanhf(lg * (1.0f / 30.0f));
        float vcur = v, vmax0 = 0.f, my_e = 0.f, sum = 0.f, prev = 0.f;
        int   my_i = 0;
        bool  ambig = false;
#pragma unroll 1
        for (int k = 0; k < TOPK + 1; ++k) {   // ranks 1..9 with margin check
            float bv = vcur;
            int   bi = lane;
#pragma unroll
            for (int s = 32; s >= 1; s >>= 1) {
                float ov = __shfl_xor(bv, s);
                int   oi = __shfl_xor(bi, s);
                if (ov > bv || (ov == bv && oi < bi)) { bv = ov; bi = oi; }
            }
            if (k == 0) vmax0 = bv;
            else        ambig |= (prev - bv < MARGIN);
            prev = bv;
            if (k < TOPK) {
                float e = __expf(bv - vmax0);
                sum += e;
                if (lane == k) { my_e = e; my_i = bi; }
                if (lane == bi) vcur = -INFINITY;
            }
        }
        if (!ambig) {
            if (lane < TOPK) {
                out_w[(size_t)t * TOPK + lane] = my_e / sum;
                out_i[(size_t)t * TOPK + lane] = (float)my_i;
            }
        } else if (lane == 0) {
            redo_list[atomicAdd(redo_cnt, 1)] = t;
        }
    }
}

// ---------------- pass 2: exact f64 redo of ambiguous tokens ---------------
__global__ __launch_bounds__(256, 2)
void gate_redo(const float* __restrict__ X, const float* __restrict__ W,
               float* __restrict__ out,
               const int* __restrict__ redo_cnt, const int* __restrict__ redo_list,
               int T) {
    __shared__ double lgs[64];
    const int lane = threadIdx.x & 63;
    const int q    = threadIdx.x >> 6;
    const int n    = *redo_cnt;
    float* out_w = out;
    float* out_i = out + (size_t)T * TOPK;

    for (int i = blockIdx.x; i < n; i += gridDim.x) {
        const int t = redo_list[i];
        const float* xr = X + (size_t)t * HIDDEN;
#pragma unroll 1
        for (int j = 0; j < 16; ++j) {
            const int e = q * 16 + j;
            const float* wr = W + (size_t)e * HIDDEN;
            double s = 0.0;
#pragma unroll 2
            for (int k = lane * 4; k < HIDDEN; k += 256) {
                float4 wv = *reinterpret_cast<const float4*>(wr + k);
                float4 xv = *reinterpret_cast<const float4*>(xr + k);
                s = fma((double)xv.x, (double)wv.x, s);
                s = fma((double)xv.y, (double)wv.y, s);
                s = fma((double)xv.z, (double)wv.z, s);
                s = fma((double)xv.w, (double)wv.w, s);
            }
#pragma unroll
            for (int sft = 32; sft >= 1; sft >>= 1) s += __shfl_xor(s, sft);
            if (lane == 0) lgs[e] = s;
        }
        __syncthreads();
        if (q == 0) {
            double vv = 30.0 * tanh(lgs[lane] * (1.0 / 30.0));
            double dmax0 = 0.0, dmy_e = 0.0, dsum = 0.0;
            int    dmy_i = 0;
#pragma unroll 1
            for (int k = 0; k < TOPK; ++k) {
                double bv = vv;
                int    bi = lane;
#pragma unroll
                for (int s = 32; s >= 1; s >>= 1) {
                    double ov = __shfl_xor(bv, s);
                    int    oi = __shfl_xor(bi, s);
                    if (ov > bv || (ov == bv && oi < bi)) { bv = ov; bi = oi; }
                }
                if (k == 0) dmax0 = bv;
                double e = exp(bv - dmax0);
                dsum += e;
                if (lane == k) { dmy_e = e; dmy_i = bi; }
                if (lane == bi) vv = -HUGE_VAL;
            }
            if (lane < TOPK) {
                out_w[(size_t)t * TOPK + lane] = (float)(dmy_e / dsum);
                out_i[(size_t)t * TOPK + lane] = (float)dmy_i;
            }
        }
        __syncthreads();
    }
}

// ---------------- fallback (round-3 proven) if ws too small ----------------
#define F_HC 64
#define F_LDS_STRIDE 68
#define F_TPW 4
#define F_TPB 16

__global__ __launch_bounds__(256, 4)
void moe_gate_fallback(const float* __restrict__ X, const float* __restrict__ W,
                       float* __restrict__ out, int T) {
    __shared__ float wlds[NEXP * F_LDS_STRIDE];
    const int tid  = threadIdx.x;
    const int lane = tid & 63;
    const int wid  = tid >> 6;
    const int t0   = blockIdx.x * F_TPB + wid * F_TPW;
    double accd[F_TPW];
#pragma unroll
    for (int m = 0; m < F_TPW; ++m) accd[m] = 0.0;
    for (int hb = 0; hb < HIDDEN; hb += F_HC) {
        __syncthreads();
#pragma unroll
        for (int k = 0; k < 4; ++k) {
            int f = tid + k * 256, e = f >> 4, c4 = f & 15;
            const float4 wv = *reinterpret_cast<const float4*>(W + e * HIDDEN + hb + c4 * 4);
            *reinterpret_cast<float4*>(&wlds[e * F_LDS_STRIDE + c4 * 4]) = wv;
        }
        __syncthreads();
        float accf[F_TPW];
#pragma unroll
        for (int m = 0; m < F_TPW; ++m) accf[m] = 0.f;
#pragma unroll 4
        for (int h4 = 0; h4 < F_HC / 4; ++h4) {
            const float4 wv = *reinterpret_cast<const float4*>(&wlds[lane * F_LDS_STRIDE + h4 * 4]);
#pragma unroll
            for (int m = 0; m < F_TPW; ++m) {
                const float4 xv = *reinterpret_cast<const float4*>(
                    X + (size_t)(t0 + m) * HIDDEN + hb + h4 * 4);
                accf[m] = fmaf(xv.x, wv.x, accf[m]);
                accf[m] = fmaf(xv.y, wv.y, accf[m]);
                accf[m] = fmaf(xv.z, wv.z, accf[m]);
                accf[m] = fmaf(xv.w, wv.w, accf[m]);
            }
        }
#pragma unroll
        for (int m = 0; m < F_TPW; ++m) accd[m] += (double)accf[m];
    }
    float* out_w = out;
    float* out_i = out + (size_t)T * TOPK;
#pragma unroll 1
    for (int m = 0; m < F_TPW; ++m) {
        const int t = t0 + m;
        double vv = 30.0 * tanh(accd[m] * (1.0 / 30.0));
        double dmax0 = 0.0, dmy_e = 0.0, dsum = 0.0;
        int dmy_i = 0;
#pragma unroll 1
        for (int k = 0; k < TOPK; ++k) {
            double bv = vv; int bi = lane;
#pragma unroll
            for (int s = 32; s >= 1; s >>= 1) {
                double ov = __shfl_xor(bv, s);
                int    oi = __shfl_xor(bi, s);
                if (ov > bv || (ov == bv && oi < bi)) { bv = ov; bi = oi; }
            }
            if (k == 0) dmax0 = bv;
            double e = exp(bv - dmax0);
            dsum += e;
            if (lane == k) { dmy_e = e; dmy_i = bi; }
            if (lane == bi) vv = -HUGE_VAL;
        }
        if (lane < TOPK) {
            out_w[(size_t)t * TOPK + lane] = (float)(dmy_e / dsum);
            out_i[(size_t)t * TOPK + lane] = (float)dmy_i;
        }
    }
}

extern "C" void kernel_launch(void* const* d_in, const int* in_sizes, int n_in,
                              void* d_out, int out_size, void* d_ws, size_t ws_size,
                              hipStream_t stream) {
    const float* X = (const float*)d_in[0];     // [4,4096,4096] fp32
    const float* W = (const float*)d_in[1];     // [64,4096] fp32
    float* out = (float*)d_out;
    const int T = in_sizes[0] / HIDDEN;         // 16384

    if (ws_size < WS_NEED) {
        hipLaunchKernelGGL(moe_gate_fallback, dim3(T / F_TPB), dim3(256), 0, stream, X, W, out, T);
        return;
    }
    char* ws = (char*)d_ws;
    int* cnt  = (int*)ws;
    int* list = (int*)(ws + WS_LIST_OFF);
    unsigned short* Whi = (unsigned short*)(ws + WS_WHI_OFF);
    unsigned short* Wlo = (unsigned short*)(ws + WS_WLO_OFF);

    hipLaunchKernelGGL(wconv_kernel, dim3(256), dim3(256), 0, stream, W, Whi, Wlo, cnt);
    hipLaunchKernelGGL(gate_mfma, dim3(T / TPB), dim3(512), 0, stream,
                       X, Whi, Wlo, out, cnt, list, T);
    hipLaunchKernelGGL(gate_redo, dim3(256), dim3(256), 0, stream,
                       X, W, out, cnt, list, T);
}